// Round 1
// baseline (106.839 us; speedup 1.0000x reference)
//
#include <hip/hip_runtime.h>
#include <hip/hip_bf16.h>
#include <stdint.h>
#include <stddef.h>

// ---------------------------------------------------------------------------
// SSRupsampling3: the whole reference collapses to
//   T' = [Wa; Wlr_mid; Wdu_mid] @ x   (relu+bias on rows 128..383)   [GEMM1]
//   out_quadrants = W2 @ T'                                          [GEMM2]
// where Wa = w_ch[:, :128] @ w_1x1,
//       W2[r=(b*256+i*2+g)] = [M | M@Wch_lr | M@Wch_du],
//       M = w_H[g*128+i, :] (row) x w_w[b*128: (b+1)*128, :]
// out[n, i, 2h+b, 2w+g] = W2[r] . T'[pixel]
// The 3x1 / 1x3 convs only use their CENTER tap (rows/cols folded to batch
// before padding -> outer taps see zeros only).
// ---------------------------------------------------------------------------

typedef __attribute__((ext_vector_type(8))) __bf16 bf16x8;
typedef __attribute__((ext_vector_type(4))) float  f32x4;
typedef __attribute__((ext_vector_type(2))) float  f32x2;
typedef __attribute__((ext_vector_type(4))) unsigned int u32x4;
typedef __attribute__((ext_vector_type(2))) unsigned int u32x2;

// ---------------- precompute kernels (run every launch, deterministic) -----

__global__ __launch_bounds__(256) void prep_wbig_k(
    const float* __restrict__ w_ch, const float* __restrict__ w_1x1,
    const float* __restrict__ w_lr, const float* __restrict__ w_du,
    __bf16* __restrict__ Wbig)  // [384][512]
{
  int gid = blockIdx.x * 256 + threadIdx.x;
  if (gid >= 384 * 512) return;
  int r = gid >> 9, c = gid & 511;
  float v;
  if (r < 128) {                      // Wa = w_ch[:, :128] @ w_1x1
    float a = 0.f;
    #pragma unroll 8
    for (int j = 0; j < 128; ++j) a += w_ch[r * 384 + j] * w_1x1[j * 512 + c];
    v = a;
  } else if (r < 256) {               // center tap of (1,3) conv
    v = w_lr[(r - 128) * 1536 + c * 3 + 1];
  } else {                            // center tap of (3,1) conv
    v = w_du[(r - 256) * 1536 + c * 3 + 1];
  }
  Wbig[gid] = (__bf16)v;
}

__global__ __launch_bounds__(256) void prep_m_k(
    const float* __restrict__ w_H, const float* __restrict__ w_w,
    float* __restrict__ Mrows)  // [512][128], row r = b*256 + i*2 + g
{
  int gid = blockIdx.x * 256 + threadIdx.x;
  if (gid >= 512 * 128) return;
  int r = gid >> 7, k = gid & 127;
  int beta = r >> 8, gam = r & 1, i = (r >> 1) & 127;
  const float* wh = w_H + (gam * 128 + i) * 128;
  const float* ww = w_w + beta * 16384 + k;
  float a = 0.f;
  #pragma unroll 8
  for (int t = 0; t < 128; ++t) a += wh[t] * ww[t * 128];
  Mrows[gid] = a;
}

__global__ __launch_bounds__(256) void prep_w2_k(
    const float* __restrict__ Mrows, const float* __restrict__ w_ch,
    __bf16* __restrict__ W2)  // [512][384]
{
  int gid = blockIdx.x * 256 + threadIdx.x;
  if (gid >= 512 * 384) return;
  int r = gid / 384, col = gid - r * 384;
  float v;
  if (col < 128) {
    v = Mrows[r * 128 + col];
  } else {                 // cols 128..383: M @ w_ch[:, 128..383]
    float a = 0.f;
    #pragma unroll 8
    for (int k = 0; k < 128; ++k) a += Mrows[r * 128 + k] * w_ch[k * 384 + col];
    v = a;
  }
  W2[gid] = (__bf16)v;
}

// ---------------- GEMM1: T'[p][384] = f(Wbig @ X) ---------------------------
// 128x128 tile, BK=64, 4 waves (2x2), 16x16x32 bf16 MFMA.
// LDS tiles [128 rows][64 k] bf16 with byte XOR swizzle ((row&7)<<4).

__global__ __launch_bounds__(256) void gemm1_k(
    const float* __restrict__ x, const __bf16* __restrict__ Wbig,
    const float* __restrict__ b_lr, const float* __restrict__ b_du,
    __bf16* __restrict__ Tp)
{
  __shared__ __bf16 Abuf[128 * 64];
  __shared__ __bf16 Bbuf[128 * 64];

  const int tid = threadIdx.x;
  const int lane = tid & 63;
  const int wv = tid >> 6;
  const int wr = wv >> 1, wc = wv & 1;
  const int l15 = lane & 15, lg = lane >> 4;

  const int bid = blockIdx.x;
  const int rt = bid % 3;          // 3 row tiles (M=384)
  const int ct = bid / 3;          // 256 pixel tiles
  const int m0 = rt * 128;
  const int p0 = ct * 128;
  const float* xb = x + (size_t)(p0 >> 12) * (512 * 4096) + (p0 & 4095);

  const int am   = tid >> 3;          // staging row within 32-row chunk
  const int akxb = (tid & 7) * 16;    // staging byte col within 128B row
  const int s_pl = (tid & 31) * 4;    // B staging: 4 pixels
  const int s_k0 = (tid >> 5) * 8;    // B staging: 8 channels

  f32x4 acc[4][4] = {};

  for (int kt = 0; kt < 8; ++kt) {
    // stage A: Wbig rows (bf16, plain copy, swizzled LDS dst)
    #pragma unroll
    for (int i = 0; i < 4; ++i) {
      int m = i * 32 + am;
      u32x4 d = *(const u32x4*)((const char*)Wbig +
                                (size_t)(m0 + m) * 1024 + kt * 128 + akxb);
      *(u32x4*)((char*)Abuf + m * 128 + (akxb ^ ((m & 7) << 4))) = d;
    }
    // stage B: x is f32 [channel][pixel]; load 8k x 4p block, convert to bf16,
    // transpose in registers, store k-contiguous per pixel row.
    f32x4 ld[8];
    #pragma unroll
    for (int j = 0; j < 8; ++j)
      ld[j] = *(const f32x4*)(xb + (size_t)(kt * 64 + s_k0 + j) * 4096 + s_pl);
    #pragma unroll
    for (int pi = 0; pi < 4; ++pi) {
      int p = s_pl + pi;
      union { __bf16 b[8]; u32x4 u; } wd;
      #pragma unroll
      for (int j = 0; j < 8; ++j) {
        float f = (pi == 0) ? ld[j].x : (pi == 1) ? ld[j].y
                : (pi == 2) ? ld[j].z : ld[j].w;
        wd.b[j] = (__bf16)f;
      }
      *(u32x4*)((char*)Bbuf + p * 128 + ((s_k0 * 2) ^ ((p & 7) << 4))) = wd.u;
    }
    __syncthreads();
    #pragma unroll
    for (int ks = 0; ks < 2; ++ks) {
      bf16x8 af[4], bfr[4];
      #pragma unroll
      for (int f = 0; f < 4; ++f) {
        int ra = wr * 64 + f * 16 + l15;
        af[f] = *(const bf16x8*)((const char*)Abuf + ra * 128 +
                                 ((ks * 64 + lg * 16) ^ ((ra & 7) << 4)));
        int rb = wc * 64 + f * 16 + l15;
        bfr[f] = *(const bf16x8*)((const char*)Bbuf + rb * 128 +
                                  ((ks * 64 + lg * 16) ^ ((rb & 7) << 4)));
      }
      #pragma unroll
      for (int i = 0; i < 4; ++i)
        #pragma unroll
        for (int j = 0; j < 4; ++j)
          acc[i][j] = __builtin_amdgcn_mfma_f32_16x16x32_bf16(
              af[i], bfr[j], acc[i][j], 0, 0, 0);
    }
    __syncthreads();
  }

  // epilogue: rows >=128 get bias+relu; store bf16 at T'[p][r] (8B per frag)
  const bool dorelu = (m0 >= 128);
  const float* bias = (m0 == 128) ? b_lr : b_du;
  #pragma unroll
  for (int i = 0; i < 4; ++i) {
    int rloc = wr * 64 + i * 16 + lg * 4;
    #pragma unroll
    for (int j = 0; j < 4; ++j) {
      int p = p0 + wc * 64 + j * 16 + l15;
      union { __bf16 b[4]; u32x2 u; } wd;
      #pragma unroll
      for (int e = 0; e < 4; ++e) {
        float v = acc[i][j][e];
        if (dorelu) v = fmaxf(v + bias[rloc + e], 0.f);
        wd.b[e] = (__bf16)v;
      }
      *(u32x2*)((char*)Tp + (size_t)p * 768 + (m0 + rloc) * 2) = wd.u;
    }
  }
}

// ---------------- GEMM2: out = W2 @ T', pixel-shuffle scatter epilogue ------

__global__ __launch_bounds__(256) void gemm2_k(
    const __bf16* __restrict__ W2, const __bf16* __restrict__ Tp,
    float* __restrict__ out)
{
  __shared__ __bf16 Abuf[128 * 64];
  __shared__ __bf16 Bbuf[128 * 64];

  const int tid = threadIdx.x;
  const int lane = tid & 63;
  const int wv = tid >> 6;
  const int wr = wv >> 1, wc = wv & 1;
  const int l15 = lane & 15, lg = lane >> 4;

  const int bid = blockIdx.x;
  const int rt = bid & 3;          // 4 row tiles (M=512)
  const int ct = bid >> 2;         // 256 pixel tiles
  const int m0 = rt * 128;
  const int p0 = ct * 128;

  const int am   = tid >> 3;
  const int akxb = (tid & 7) * 16;

  f32x4 acc[4][4] = {};

  for (int kt = 0; kt < 6; ++kt) {   // K = 384
    #pragma unroll
    for (int i = 0; i < 4; ++i) {
      int m = i * 32 + am;
      u32x4 da = *(const u32x4*)((const char*)W2 +
                                 (size_t)(m0 + m) * 768 + kt * 128 + akxb);
      *(u32x4*)((char*)Abuf + m * 128 + (akxb ^ ((m & 7) << 4))) = da;
      u32x4 db = *(const u32x4*)((const char*)Tp +
                                 (size_t)(p0 + m) * 768 + kt * 128 + akxb);
      *(u32x4*)((char*)Bbuf + m * 128 + (akxb ^ ((m & 7) << 4))) = db;
    }
    __syncthreads();
    #pragma unroll
    for (int ks = 0; ks < 2; ++ks) {
      bf16x8 af[4], bfr[4];
      #pragma unroll
      for (int f = 0; f < 4; ++f) {
        int ra = wr * 64 + f * 16 + l15;
        af[f] = *(const bf16x8*)((const char*)Abuf + ra * 128 +
                                 ((ks * 64 + lg * 16) ^ ((ra & 7) << 4)));
        int rb = wc * 64 + f * 16 + l15;
        bfr[f] = *(const bf16x8*)((const char*)Bbuf + rb * 128 +
                                  ((ks * 64 + lg * 16) ^ ((rb & 7) << 4)));
      }
      #pragma unroll
      for (int i = 0; i < 4; ++i)
        #pragma unroll
        for (int j = 0; j < 4; ++j)
          acc[i][j] = __builtin_amdgcn_mfma_f32_16x16x32_bf16(
              af[i], bfr[j], acc[i][j], 0, 0, 0);
    }
    __syncthreads();
  }

  // epilogue: row r = b*256 + i*2 + g -> out[n, i, 2h+b, 2w+g].
  // MFMA C layout rows (lane>>4)*4 + reg -> reg pairs are (g=0, g=1): float2.
  const int nimg = p0 >> 12;
  #pragma unroll
  for (int i = 0; i < 4; ++i) {
    int r = m0 + wr * 64 + i * 16 + lg * 4;   // even
    int beta = r >> 8;
    int irow = (r >> 1) & 127;
    #pragma unroll
    for (int j = 0; j < 4; ++j) {
      int p = p0 + wc * 64 + j * 16 + l15;
      int h = (p >> 6) & 63, w = p & 63;
      size_t o0 = ((((size_t)nimg * 128 + irow) * 128) + (2 * h + beta)) * 128
                  + 2 * w;
      f32x2 lo; lo.x = acc[i][j][0]; lo.y = acc[i][j][1];
      f32x2 hi; hi.x = acc[i][j][2]; hi.y = acc[i][j][3];
      *(f32x2*)(out + o0)         = lo;   // channel irow
      *(f32x2*)(out + o0 + 16384) = hi;   // channel irow+1
    }
  }
}

// ---------------- launcher ---------------------------------------------------

extern "C" void kernel_launch(void* const* d_in, const int* in_sizes, int n_in,
                              void* d_out, int out_size, void* d_ws, size_t ws_size,
                              hipStream_t stream) {
  const float* x     = (const float*)d_in[0];
  const float* w_du  = (const float*)d_in[1];
  const float* b_du  = (const float*)d_in[2];
  const float* w_lr  = (const float*)d_in[3];
  const float* b_lr  = (const float*)d_in[4];
  const float* w_1x1 = (const float*)d_in[5];
  const float* w_ch  = (const float*)d_in[6];
  const float* w_w   = (const float*)d_in[7];
  const float* w_H   = (const float*)d_in[8];
  float* out = (float*)d_out;

  char* ws = (char*)d_ws;
  __bf16* Wbig  = (__bf16*)(ws + 0);         // 384*512*2  = 393216
  float*  Mrows = (float*) (ws + 393216);    // 512*128*4  = 262144
  __bf16* W2    = (__bf16*)(ws + 655360);    // 512*384*2  = 393216
  __bf16* Tp    = (__bf16*)(ws + 1048576);   // 32768*384*2 = 25165824
  if (ws_size < (size_t)26214400) return;    // needs ~25 MiB workspace

  prep_wbig_k<<<768, 256, 0, stream>>>(w_ch, w_1x1, w_lr, w_du, Wbig);
  prep_m_k   <<<256, 256, 0, stream>>>(w_H, w_w, Mrows);
  prep_w2_k  <<<768, 256, 0, stream>>>(Mrows, w_ch, W2);
  gemm1_k    <<<768, 256, 0, stream>>>(x, Wbig, b_lr, b_du, Tp);
  gemm2_k    <<<1024, 256, 0, stream>>>(W2, Tp, out);
}

// Round 2
// 87.930 us; speedup vs baseline: 1.2150x; 1.2150x over previous
//
#include <hip/hip_runtime.h>
#include <hip/hip_bf16.h>
#include <stdint.h>
#include <stddef.h>

// ---------------------------------------------------------------------------
// SSRupsampling3 collapses to:
//   T  = f(Wbig[384x512] @ x)    (relu+bias on rows 128..383)
//   out= W2[512x384] @ T          (+ pixel-shuffle scatter)
// Fused kernel: one block = 64 pixels; T kept in LDS between the two GEMMs.
// Wbig = [w_ch[:, :128] @ w_1x1 ; w_lr center tap ; w_du center tap]
// W2[r=(b*256+i*2+g)] = [M | M@Wch_lr | M@Wch_du],  M = outer(w_H[g*128+i], w_w[b*128..])
// out[n, i, 2h+b, 2w+g] = W2[r] . T[:, pixel]
// ---------------------------------------------------------------------------

typedef __attribute__((ext_vector_type(8))) __bf16 bf16x8;
typedef __attribute__((ext_vector_type(4))) float  f32x4;
typedef __attribute__((ext_vector_type(2))) float  f32x2;
typedef __attribute__((ext_vector_type(4))) unsigned int u32x4;
typedef __attribute__((ext_vector_type(2))) unsigned int u32x2;

// ---------------- precompute kernels (unchanged from R1, verified) ----------

__global__ __launch_bounds__(256) void prep_wbig_k(
    const float* __restrict__ w_ch, const float* __restrict__ w_1x1,
    const float* __restrict__ w_lr, const float* __restrict__ w_du,
    __bf16* __restrict__ Wbig)  // [384][512]
{
  int gid = blockIdx.x * 256 + threadIdx.x;
  if (gid >= 384 * 512) return;
  int r = gid >> 9, c = gid & 511;
  float v;
  if (r < 128) {
    float a = 0.f;
    #pragma unroll 8
    for (int j = 0; j < 128; ++j) a += w_ch[r * 384 + j] * w_1x1[j * 512 + c];
    v = a;
  } else if (r < 256) {
    v = w_lr[(r - 128) * 1536 + c * 3 + 1];
  } else {
    v = w_du[(r - 256) * 1536 + c * 3 + 1];
  }
  Wbig[gid] = (__bf16)v;
}

__global__ __launch_bounds__(256) void prep_m_k(
    const float* __restrict__ w_H, const float* __restrict__ w_w,
    float* __restrict__ Mrows)  // [512][128]
{
  int gid = blockIdx.x * 256 + threadIdx.x;
  if (gid >= 512 * 128) return;
  int r = gid >> 7, k = gid & 127;
  int beta = r >> 8, gam = r & 1, i = (r >> 1) & 127;
  const float* wh = w_H + (gam * 128 + i) * 128;
  const float* ww = w_w + beta * 16384 + k;
  float a = 0.f;
  #pragma unroll 8
  for (int t = 0; t < 128; ++t) a += wh[t] * ww[t * 128];
  Mrows[gid] = a;
}

__global__ __launch_bounds__(256) void prep_w2_k(
    const float* __restrict__ Mrows, const float* __restrict__ w_ch,
    __bf16* __restrict__ W2)  // [512][384]
{
  int gid = blockIdx.x * 256 + threadIdx.x;
  if (gid >= 512 * 384) return;
  int r = gid / 384, col = gid - r * 384;
  float v;
  if (col < 128) {
    v = Mrows[r * 128 + col];
  } else {
    float a = 0.f;
    #pragma unroll 8
    for (int k = 0; k < 128; ++k) a += Mrows[r * 128 + k] * w_ch[k * 384 + col];
    v = a;
  }
  W2[gid] = (__bf16)v;
}

// ---------------- fused kernel ----------------------------------------------
// 512 threads (8 waves, 4M x 2N), 64 pixels/block, grid 512.
// LDS (112 KiB): Tlds 64x768B (T', pixel-major, k-contig, XOR-swizzled)
//                Stg  64 KiB   (phase1: A1 384x128B + B1 64x128B; phase2: A2 512x128B)

__global__ __launch_bounds__(512, 2) void fused_k(
    const float* __restrict__ x, const __bf16* __restrict__ Wbig,
    const __bf16* __restrict__ W2,
    const float* __restrict__ b_lr, const float* __restrict__ b_du,
    float* __restrict__ out)
{
  __shared__ __align__(16) char smem[114688];
  char* Tlds = smem;               // 64 * 768
  char* A1   = smem + 49152;       // 384 * 128
  char* B1   = smem + 49152 + 49152; // 64 * 128
  char* A2   = smem + 49152;       // 512 * 128 (reuses A1+B1 region)

  const int tid  = threadIdx.x;
  const int lane = tid & 63;
  const int wv   = tid >> 6;       // 0..7
  const int wr   = wv >> 1;        // 0..3 (M)
  const int wc   = wv & 1;         // 0..1 (N)
  const int l15  = lane & 15, lg = lane >> 4;

  const int p0      = blockIdx.x * 64;
  const int img     = p0 >> 12;
  const int pixbase = p0 & 4095;
  const float* xb   = x + (size_t)img * (512 * 4096) + pixbase;

  // ---------------- phase 1: T = f(Wbig @ x_tile) ----------------
  f32x4 acc1[6][2] = {};
  const int bs_p = (tid & 15) * 4;          // B staging: pixel base (tid<128)
  const int bs_k = ((tid >> 4) & 7) * 8;    // B staging: channel base

  for (int kt = 0; kt < 8; ++kt) {
    if (tid < 128) {
      // stage B1: x[64ch x 64px] f32 -> bf16, k-contiguous per pixel row
      f32x4 ld[8];
      #pragma unroll
      for (int j = 0; j < 8; ++j)
        ld[j] = *(const f32x4*)(xb + (size_t)(kt * 64 + bs_k + j) * 4096 + bs_p);
      #pragma unroll
      for (int pi = 0; pi < 4; ++pi) {
        int p = bs_p + pi;
        union { __bf16 b[8]; u32x4 u; } wd;
        #pragma unroll
        for (int j = 0; j < 8; ++j) {
          float f = (pi == 0) ? ld[j].x : (pi == 1) ? ld[j].y
                  : (pi == 2) ? ld[j].z : ld[j].w;
          wd.b[j] = (__bf16)f;
        }
        *(u32x4*)(B1 + p * 128 + ((bs_k * 2) ^ ((p & 7) << 4))) = wd.u;
      }
    } else {
      // stage A1: Wbig[384][kt*64 .. +64] bf16 copy, swizzled
      int t2 = tid - 128;
      #pragma unroll
      for (int i = 0; i < 8; ++i) {
        int q = t2 + i * 384;
        int row = q >> 3, bc = (q & 7) * 16;
        u32x4 d = *(const u32x4*)((const char*)Wbig +
                                  (size_t)row * 1024 + kt * 128 + bc);
        *(u32x4*)(A1 + row * 128 + (bc ^ ((row & 7) << 4))) = d;
      }
    }
    __syncthreads();
    #pragma unroll
    for (int ks = 0; ks < 2; ++ks) {
      bf16x8 af[6], bfr[2];
      #pragma unroll
      for (int i = 0; i < 6; ++i) {
        int ra = wr * 96 + i * 16 + l15;
        af[i] = *(const bf16x8*)(A1 + ra * 128 +
                                 ((ks * 64 + lg * 16) ^ ((ra & 7) << 4)));
      }
      #pragma unroll
      for (int j = 0; j < 2; ++j) {
        int rb = wc * 32 + j * 16 + l15;
        bfr[j] = *(const bf16x8*)(B1 + rb * 128 +
                                  ((ks * 64 + lg * 16) ^ ((rb & 7) << 4)));
      }
      #pragma unroll
      for (int i = 0; i < 6; ++i)
        #pragma unroll
        for (int j = 0; j < 2; ++j)
          acc1[i][j] = __builtin_amdgcn_mfma_f32_16x16x32_bf16(
              af[i], bfr[j], acc1[i][j], 0, 0, 0);
    }
    __syncthreads();
  }

  // epilogue 1: bias+relu (rows >=128), write T to Tlds [pixel][384k] bf16
  #pragma unroll
  for (int i = 0; i < 6; ++i) {
    int mb = wr * 96 + i * 16 + lg * 4;   // 16-row frag entirely in one region
    const float* bias = (mb >= 256) ? (b_du + (mb - 256))
                      : (mb >= 128) ? (b_lr + (mb - 128)) : nullptr;
    #pragma unroll
    for (int j = 0; j < 2; ++j) {
      int p = wc * 32 + j * 16 + l15;
      union { __bf16 b[4]; u32x2 u; } wd;
      #pragma unroll
      for (int e = 0; e < 4; ++e) {
        float v = acc1[i][j][e];
        if (mb >= 128) v = fmaxf(v + bias[e], 0.f);
        wd.b[e] = (__bf16)v;
      }
      *(u32x2*)(Tlds + p * 768 + ((mb * 2) ^ ((p & 7) << 4))) = wd.u;
    }
  }
  __syncthreads();

  // ---------------- phase 2: out = W2 @ T ----------------
  f32x4 acc2[8][2] = {};
  for (int kt = 0; kt < 6; ++kt) {
    #pragma unroll
    for (int i = 0; i < 8; ++i) {
      int q = tid + i * 512;
      int row = q >> 3, bc = (q & 7) * 16;
      u32x4 d = *(const u32x4*)((const char*)W2 +
                                (size_t)row * 768 + kt * 128 + bc);
      *(u32x4*)(A2 + row * 128 + (bc ^ ((row & 7) << 4))) = d;
    }
    __syncthreads();
    #pragma unroll
    for (int ks = 0; ks < 2; ++ks) {
      bf16x8 af[8], bfr[2];
      #pragma unroll
      for (int i = 0; i < 8; ++i) {
        int ra = wr * 128 + i * 16 + l15;
        af[i] = *(const bf16x8*)(A2 + ra * 128 +
                                 ((ks * 64 + lg * 16) ^ ((ra & 7) << 4)));
      }
      #pragma unroll
      for (int j = 0; j < 2; ++j) {
        int rb = wc * 32 + j * 16 + l15;
        bfr[j] = *(const bf16x8*)(Tlds + rb * 768 +
                                  ((kt * 128 + ks * 64 + lg * 16) ^ ((rb & 7) << 4)));
      }
      #pragma unroll
      for (int i = 0; i < 8; ++i)
        #pragma unroll
        for (int j = 0; j < 2; ++j)
          acc2[i][j] = __builtin_amdgcn_mfma_f32_16x16x32_bf16(
              af[i], bfr[j], acc2[i][j], 0, 0, 0);
    }
    __syncthreads();
  }

  // epilogue 2: pixel-shuffle scatter. row r = b*256 + i*2 + g.
  #pragma unroll
  for (int i = 0; i < 8; ++i) {
    int r = wr * 128 + i * 16 + lg * 4;   // even
    int beta = r >> 8;
    int irow = (r >> 1) & 127;
    #pragma unroll
    for (int j = 0; j < 2; ++j) {
      int pp = pixbase + wc * 32 + j * 16 + l15;
      int h = pp >> 6, w = pp & 63;
      size_t o0 = ((((size_t)img * 128 + irow) * 128) + (2 * h + beta)) * 128
                  + 2 * w;
      f32x2 lo; lo.x = acc2[i][j][0]; lo.y = acc2[i][j][1];
      f32x2 hi; hi.x = acc2[i][j][2]; hi.y = acc2[i][j][3];
      *(f32x2*)(out + o0)         = lo;   // channel irow
      *(f32x2*)(out + o0 + 16384) = hi;   // channel irow+1
    }
  }
}

// ---------------- launcher ---------------------------------------------------

extern "C" void kernel_launch(void* const* d_in, const int* in_sizes, int n_in,
                              void* d_out, int out_size, void* d_ws, size_t ws_size,
                              hipStream_t stream) {
  const float* x     = (const float*)d_in[0];
  const float* w_du  = (const float*)d_in[1];
  const float* b_du  = (const float*)d_in[2];
  const float* w_lr  = (const float*)d_in[3];
  const float* b_lr  = (const float*)d_in[4];
  const float* w_1x1 = (const float*)d_in[5];
  const float* w_ch  = (const float*)d_in[6];
  const float* w_w   = (const float*)d_in[7];
  const float* w_H   = (const float*)d_in[8];
  float* out = (float*)d_out;

  char* ws = (char*)d_ws;
  __bf16* Wbig  = (__bf16*)(ws + 0);         // 384*512*2  = 393216
  float*  Mrows = (float*) (ws + 393216);    // 512*128*4  = 262144
  __bf16* W2    = (__bf16*)(ws + 655360);    // 512*384*2  = 393216
  if (ws_size < (size_t)1048576) return;

  prep_wbig_k<<<768, 256, 0, stream>>>(w_ch, w_1x1, w_lr, w_du, Wbig);
  prep_m_k   <<<256, 256, 0, stream>>>(w_H, w_w, Mrows);
  prep_w2_k  <<<768, 256, 0, stream>>>(Mrows, w_ch, W2);
  fused_k    <<<512, 512, 0, stream>>>(x, Wbig, W2, b_lr, b_du, out);
}

// Round 3
// 63.749 us; speedup vs baseline: 1.6759x; 1.3793x over previous
//
#include <hip/hip_runtime.h>
#include <hip/hip_bf16.h>
#include <stdint.h>
#include <stddef.h>

// ---------------------------------------------------------------------------
// SSRupsampling3 == two small GEMMs:
//   T  = f(Wbig[384x512] @ x)     (relu+bias rows 128..383)
//   out= W2[512x384] @ T          (+ pixel-shuffle scatter)
// R3 structure: weights pre-swizzled into MFMA A-fragment order; loaded
// global->register (L2-resident, no LDS, no barriers). Only x goes through
// LDS (f32->bf16 transpose staging, double-buffered). T lives in LDS.
// 512 thr (8 waves, pure M-split), 64 px/block, grid 512, 2 blocks/CU.
// ---------------------------------------------------------------------------

typedef __attribute__((ext_vector_type(8))) __bf16 bf16x8;
typedef __attribute__((ext_vector_type(4))) float  f32x4;
typedef __attribute__((ext_vector_type(2))) float  f32x2;
typedef __attribute__((ext_vector_type(4))) unsigned int u32x4;
typedef __attribute__((ext_vector_type(2))) unsigned int u32x2;

// A-fragment layout for mfma_f32_16x16x32_bf16 (verified R1/R2):
//   lane l holds A[row = mfrag*16 + (l&15)][k = gks*32 + (l>>4)*8 + j], j=0..7
// Stored as frag[(gks*NMF + mfrag)*512 + lane*8 + j] (bf16 elements).

// ---------------- single prep kernel ----------------------------------------
// blocks 0..767:   Wbig fragments (NMF=24, K=512 -> gks 0..15)
// blocks 768..1023: W2 fragments (NMF=32, K=384 -> gks 0..11), 2 rows/block

__global__ __launch_bounds__(256) void prep_k(
    const float* __restrict__ w_ch, const float* __restrict__ w_1x1,
    const float* __restrict__ w_lr, const float* __restrict__ w_du,
    const float* __restrict__ w_H,  const float* __restrict__ w_w,
    __bf16* __restrict__ Wf, __bf16* __restrict__ W2f)
{
  __shared__ float wh[2][128];
  __shared__ float Mrow[2][128];
  int bid = blockIdx.x;
  if (bid < 768) {
    int gid = bid * 256 + threadIdx.x;       // 196608 = 384*512
    int r = gid >> 9, c = gid & 511;
    float v;
    if (r < 128) {                            // w_ch[:, :128] @ w_1x1
      float a = 0.f;
      #pragma unroll 8
      for (int j = 0; j < 128; ++j) a += w_ch[r * 384 + j] * w_1x1[j * 512 + c];
      v = a;
    } else if (r < 256) {
      v = w_lr[(r - 128) * 1536 + c * 3 + 1]; // center tap (1,3)
    } else {
      v = w_du[(r - 256) * 1536 + c * 3 + 1]; // center tap (3,1)
    }
    int gks = c >> 5, lsub = (c >> 3) & 3, jj = c & 7;
    int mfrag = r >> 4, lrow = r & 15;
    Wf[((gks * 24 + mfrag) << 9) + ((lrow + 16 * lsub) << 3) + jj] = (__bf16)v;
  } else {
    int t = threadIdx.x & 127, half = threadIdx.x >> 7;
    int r = (bid - 768) * 2 + half;           // W2 row, 0..511
    int beta = r >> 8, gam = r & 1, irow = (r >> 1) & 127;
    wh[half][t] = w_H[(gam * 128 + irow) * 128 + t];
    __syncthreads();
    float a = 0.f;
    #pragma unroll 8
    for (int s = 0; s < 128; ++s) a += wh[half][s] * w_w[beta * 16384 + s * 128 + t];
    Mrow[half][t] = a;
    __syncthreads();
    int mfrag = r >> 4, lrow = r & 15;
    #pragma unroll
    for (int c0 = 0; c0 < 384; c0 += 128) {
      int col = c0 + t;
      float v;
      if (c0 == 0) {
        v = Mrow[half][t];
      } else {
        float a2 = 0.f;
        #pragma unroll 8
        for (int k = 0; k < 128; ++k) a2 += Mrow[half][k] * w_ch[k * 384 + col];
        v = a2;
      }
      int gks = col >> 5, lsub = (col >> 3) & 3, jj = col & 7;
      W2f[((gks * 32 + mfrag) << 9) + ((lrow + 16 * lsub) << 3) + jj] = (__bf16)v;
    }
  }
}

// ---------------- fused kernel ----------------------------------------------

__device__ __forceinline__ int swzB(int px) {
  return (((px & 7) ^ ((px >> 3) & 7)) << 4);
}

__global__ __launch_bounds__(512, 4) void fused_k(
    const float* __restrict__ x, const __bf16* __restrict__ Wf,
    const __bf16* __restrict__ W2f,
    const float* __restrict__ b_lr, const float* __restrict__ b_du,
    float* __restrict__ out)
{
  __shared__ __align__(16) char smem[49152 + 16384];
  char* Tlds = smem;                 // 64 px * 768 B (384 k bf16), swizzled
  char* B1   = smem + 49152;         // 2 x (64 px * 128 B)

  const int tid  = threadIdx.x;
  const int lane = tid & 63;
  const int wv   = tid >> 6;          // 0..7
  const int l15  = lane & 15, lg = lane >> 4;

  const int p0      = blockIdx.x * 64;
  const int img     = p0 >> 12;
  const int pixbase = p0 & 4095;
  const float* xb   = x + (size_t)img * (512 * 4096) + pixbase;
  const char* Wfb   = (const char*)Wf;
  const char* W2b   = (const char*)W2f;

  // B staging: 256 threads, each 4 px * 4 k (f32x4 loads, bf16x4 LDS writes)
  const bool stager = (tid < 256);
  const int sp4 = (tid & 15) * 4;
  const int sk4 = ((tid >> 4) & 15) * 4;

  f32x4 ld[4];
  auto issueB = [&](int kt) {
    if (stager) {
      #pragma unroll
      for (int j = 0; j < 4; ++j)
        ld[j] = *(const f32x4*)(xb + (size_t)(kt * 64 + sk4 + j) * 4096 + sp4);
    }
  };
  auto writeB = [&](int kt) {
    if (stager) {
      char* bw = B1 + (kt & 1) * 8192;
      #pragma unroll
      for (int pi = 0; pi < 4; ++pi) {
        int px = sp4 + pi;
        union { __bf16 b[4]; u32x2 u; } wd;
        #pragma unroll
        for (int kk = 0; kk < 4; ++kk) wd.b[kk] = (__bf16)ld[kk][pi];
        *(u32x2*)(bw + px * 128 + ((sk4 * 2) ^ swzB(px))) = wd.u;
      }
    }
  };

  // ---------------- phase 1: T = f(Wbig @ x_tile) ----------------
  issueB(0); writeB(0);
  __syncthreads();

  f32x4 acc1[3][4] = {};
  #pragma unroll 1
  for (int kt = 0; kt < 8; ++kt) {
    if (kt < 7) issueB(kt + 1);
    bf16x8 af[2][3];
    #pragma unroll
    for (int ks = 0; ks < 2; ++ks)
      #pragma unroll
      for (int i = 0; i < 3; ++i)
        af[ks][i] = *(const bf16x8*)(Wfb +
            (((kt * 2 + ks) * 24 + wv * 3 + i) << 10) + lane * 16);
    const char* bbuf = B1 + (kt & 1) * 8192;
    #pragma unroll
    for (int ks = 0; ks < 2; ++ks) {
      bf16x8 bfr[4];
      #pragma unroll
      for (int j = 0; j < 4; ++j) {
        int rb = j * 16 + l15;
        bfr[j] = *(const bf16x8*)(bbuf + rb * 128 +
                                  ((ks * 64 + lg * 16) ^ swzB(rb)));
      }
      #pragma unroll
      for (int i = 0; i < 3; ++i)
        #pragma unroll
        for (int j = 0; j < 4; ++j)
          acc1[i][j] = __builtin_amdgcn_mfma_f32_16x16x32_bf16(
              af[ks][i], bfr[j], acc1[i][j], 0, 0, 0);
    }
    if (kt < 7) writeB(kt + 1);
    __syncthreads();
  }

  // epilogue 1: bias+relu rows>=128, write T' to Tlds [px][384] bf16
  #pragma unroll
  for (int i = 0; i < 3; ++i) {
    int m0 = wv * 48 + i * 16 + lg * 4;
    bool rl = (m0 >= 128);
    const float* bp = (m0 >= 256) ? (b_du + (m0 - 256)) : (b_lr + (m0 - 128));
    float b0 = 0.f, b1 = 0.f, b2 = 0.f, b3 = 0.f;
    if (rl) { b0 = bp[0]; b1 = bp[1]; b2 = bp[2]; b3 = bp[3]; }
    #pragma unroll
    for (int j = 0; j < 4; ++j) {
      int p = j * 16 + l15;
      union { __bf16 b[4]; u32x2 u; } wd;
      float v0 = acc1[i][j][0], v1 = acc1[i][j][1];
      float v2 = acc1[i][j][2], v3 = acc1[i][j][3];
      if (rl) {
        v0 = fmaxf(v0 + b0, 0.f); v1 = fmaxf(v1 + b1, 0.f);
        v2 = fmaxf(v2 + b2, 0.f); v3 = fmaxf(v3 + b3, 0.f);
      }
      wd.b[0] = (__bf16)v0; wd.b[1] = (__bf16)v1;
      wd.b[2] = (__bf16)v2; wd.b[3] = (__bf16)v3;
      *(u32x2*)(Tlds + p * 768 + ((m0 * 2) ^ ((p & 7) << 4))) = wd.u;
    }
  }
  __syncthreads();

  // ---------------- phase 2: out = W2 @ T (barrier-free K loop) -------------
  f32x4 acc2[4][4] = {};
  bf16x8 afA[4], afB[4];
  #pragma unroll
  for (int i = 0; i < 4; ++i)
    afA[i] = *(const bf16x8*)(W2b + ((0 * 32 + wv * 4 + i) << 10) + lane * 16);

  #pragma unroll 1
  for (int g2 = 0; g2 < 6; ++g2) {
    int gA = 2 * g2, gB = 2 * g2 + 1;
    #pragma unroll
    for (int i = 0; i < 4; ++i)
      afB[i] = *(const bf16x8*)(W2b + ((gB * 32 + wv * 4 + i) << 10) + lane * 16);
    {
      bf16x8 bfr[4];
      #pragma unroll
      for (int j = 0; j < 4; ++j) {
        int rb = j * 16 + l15;
        bfr[j] = *(const bf16x8*)(Tlds + rb * 768 +
                                  ((gA * 64 + lg * 16) ^ ((rb & 7) << 4)));
      }
      #pragma unroll
      for (int i = 0; i < 4; ++i)
        #pragma unroll
        for (int j = 0; j < 4; ++j)
          acc2[i][j] = __builtin_amdgcn_mfma_f32_16x16x32_bf16(
              afA[i], bfr[j], acc2[i][j], 0, 0, 0);
    }
    if (g2 < 5) {
      #pragma unroll
      for (int i = 0; i < 4; ++i)
        afA[i] = *(const bf16x8*)(W2b + (((gA + 2) * 32 + wv * 4 + i) << 10) + lane * 16);
    }
    {
      bf16x8 bfr[4];
      #pragma unroll
      for (int j = 0; j < 4; ++j) {
        int rb = j * 16 + l15;
        bfr[j] = *(const bf16x8*)(Tlds + rb * 768 +
                                  ((gB * 64 + lg * 16) ^ ((rb & 7) << 4)));
      }
      #pragma unroll
      for (int i = 0; i < 4; ++i)
        #pragma unroll
        for (int j = 0; j < 4; ++j)
          acc2[i][j] = __builtin_amdgcn_mfma_f32_16x16x32_bf16(
              afB[i], bfr[j], acc2[i][j], 0, 0, 0);
    }
  }

  // epilogue 2: pixel-shuffle scatter. row r = beta*256 + irow*2 + gamma.
  #pragma unroll
  for (int i = 0; i < 4; ++i) {
    int r = (wv * 4 + i) * 16 + lg * 4;   // even
    int beta = r >> 8;
    int irow = (r >> 1) & 127;
    #pragma unroll
    for (int j = 0; j < 4; ++j) {
      int pp = pixbase + j * 16 + l15;
      int h = pp >> 6, w = pp & 63;
      size_t o0 = ((((size_t)img * 128 + irow) * 128) + (2 * h + beta)) * 128
                  + 2 * w;
      f32x2 lo; lo.x = acc2[i][j][0]; lo.y = acc2[i][j][1];
      f32x2 hi; hi.x = acc2[i][j][2]; hi.y = acc2[i][j][3];
      *(f32x2*)(out + o0)         = lo;   // channel irow
      *(f32x2*)(out + o0 + 16384) = hi;   // channel irow+1
    }
  }
}

// ---------------- launcher ---------------------------------------------------

extern "C" void kernel_launch(void* const* d_in, const int* in_sizes, int n_in,
                              void* d_out, int out_size, void* d_ws, size_t ws_size,
                              hipStream_t stream) {
  const float* x     = (const float*)d_in[0];
  const float* w_du  = (const float*)d_in[1];
  const float* b_du  = (const float*)d_in[2];
  const float* w_lr  = (const float*)d_in[3];
  const float* b_lr  = (const float*)d_in[4];
  const float* w_1x1 = (const float*)d_in[5];
  const float* w_ch  = (const float*)d_in[6];
  const float* w_w   = (const float*)d_in[7];
  const float* w_H   = (const float*)d_in[8];
  float* out = (float*)d_out;

  char* ws = (char*)d_ws;
  __bf16* Wf  = (__bf16*)(ws + 0);        // 16*24*1024 = 393216
  __bf16* W2f = (__bf16*)(ws + 393216);   // 12*32*1024 = 393216
  if (ws_size < (size_t)786432) return;

  prep_k <<<1024, 256, 0, stream>>>(w_ch, w_1x1, w_lr, w_du, w_H, w_w, Wf, W2f);
  fused_k<<<512, 512, 0, stream>>>(x, Wf, W2f, b_lr, b_du, out);
}

// Round 4
// 51.952 us; speedup vs baseline: 2.0565x; 1.2271x over previous
//
#include <hip/hip_runtime.h>
#include <hip/hip_bf16.h>
#include <stdint.h>
#include <stddef.h>

// ---------------------------------------------------------------------------
// SSRupsampling3 == two small GEMMs:
//   T  = f(Wbig[384x512] @ x)     (relu+bias rows 128..383)
//   out= W2[512x384] @ T          (+ pixel-shuffle scatter)
// R4: raw s_barrier (no vmcnt drain) + 2-deep x prefetch (T3/T4),
// conflict-free 4B staging writes, fast prep dots.
// ---------------------------------------------------------------------------

typedef __attribute__((ext_vector_type(8))) __bf16 bf16x8;
typedef __attribute__((ext_vector_type(4))) float  f32x4;
typedef __attribute__((ext_vector_type(2))) float  f32x2;
typedef __attribute__((ext_vector_type(4))) unsigned int u32x4;
typedef __attribute__((ext_vector_type(2))) unsigned int u32x2;

// LDS-only cross-wave dataflow -> lgkmcnt(0)+s_barrier suffices; keeps
// global prefetch loads in flight across the barrier (T3/T4).
#define BAR() asm volatile("s_waitcnt lgkmcnt(0)\n\ts_barrier" ::: "memory")

// A-fragment layout for mfma_f32_16x16x32_bf16 (verified R1-R3):
//   lane l holds A[row = mfrag*16 + (l&15)][k = gks*32 + (l>>4)*8 + j]
// Stored as frag[(gks*NMF + mfrag)*512 + lane*8 + j] (bf16).

// ---------------- prep kernel -----------------------------------------------

__global__ __launch_bounds__(256) void prep_k(
    const float* __restrict__ w_ch, const float* __restrict__ w_1x1,
    const float* __restrict__ w_lr, const float* __restrict__ w_du,
    const float* __restrict__ w_H,  const float* __restrict__ w_w,
    __bf16* __restrict__ Wf, __bf16* __restrict__ W2f)
{
  __shared__ float wh[2][128];
  __shared__ float Mrow[2][128];
  int bid = blockIdx.x;
  if (bid < 768) {
    int gid = bid * 256 + threadIdx.x;       // 196608 = 384*512
    int r = gid >> 9, c = gid & 511;
    float v;
    if (r < 128) {                            // w_ch[:, :128] @ w_1x1
      const float* a_ = w_ch + r * 384;
      const float* b_ = w_1x1 + c;
      float s0 = 0.f, s1 = 0.f, s2 = 0.f, s3 = 0.f;
      #pragma unroll
      for (int j = 0; j < 128; j += 4) {
        s0 += a_[j + 0] * b_[(size_t)(j + 0) * 512];
        s1 += a_[j + 1] * b_[(size_t)(j + 1) * 512];
        s2 += a_[j + 2] * b_[(size_t)(j + 2) * 512];
        s3 += a_[j + 3] * b_[(size_t)(j + 3) * 512];
      }
      v = (s0 + s1) + (s2 + s3);
    } else if (r < 256) {
      v = w_lr[(r - 128) * 1536 + c * 3 + 1]; // center tap (1,3)
    } else {
      v = w_du[(r - 256) * 1536 + c * 3 + 1]; // center tap (3,1)
    }
    int gks = c >> 5, lsub = (c >> 3) & 3, jj = c & 7;
    int mfrag = r >> 4, lrow = r & 15;
    Wf[((gks * 24 + mfrag) << 9) + ((lrow + 16 * lsub) << 3) + jj] = (__bf16)v;
  } else {
    int t = threadIdx.x & 127, half = threadIdx.x >> 7;
    int r = (bid - 768) * 2 + half;           // W2 row, 0..511
    int beta = r >> 8, gam = r & 1, irow = (r >> 1) & 127;
    wh[half][t] = w_H[(gam * 128 + irow) * 128 + t];
    __syncthreads();
    {
      const float* ww = w_w + beta * 16384 + t;
      float s0 = 0.f, s1 = 0.f, s2 = 0.f, s3 = 0.f;
      #pragma unroll
      for (int s = 0; s < 128; s += 4) {
        s0 += wh[half][s + 0] * ww[(s + 0) * 128];
        s1 += wh[half][s + 1] * ww[(s + 1) * 128];
        s2 += wh[half][s + 2] * ww[(s + 2) * 128];
        s3 += wh[half][s + 3] * ww[(s + 3) * 128];
      }
      Mrow[half][t] = (s0 + s1) + (s2 + s3);
    }
    __syncthreads();
    int mfrag = r >> 4, lrow = r & 15;
    #pragma unroll
    for (int c0 = 0; c0 < 384; c0 += 128) {
      int col = c0 + t;
      float v;
      if (c0 == 0) {
        v = Mrow[half][t];
      } else {
        const float* wc = w_ch + col;
        float s0 = 0.f, s1 = 0.f, s2 = 0.f, s3 = 0.f;
        #pragma unroll
        for (int k = 0; k < 128; k += 4) {
          s0 += Mrow[half][k + 0] * wc[(k + 0) * 384];
          s1 += Mrow[half][k + 1] * wc[(k + 1) * 384];
          s2 += Mrow[half][k + 2] * wc[(k + 2) * 384];
          s3 += Mrow[half][k + 3] * wc[(k + 3) * 384];
        }
        v = (s0 + s1) + (s2 + s3);
      }
      int gks = col >> 5, lsub = (col >> 3) & 3, jj = col & 7;
      W2f[((gks * 32 + mfrag) << 9) + ((lrow + 16 * lsub) << 3) + jj] = (__bf16)v;
    }
  }
}

// ---------------- fused kernel ----------------------------------------------

__device__ __forceinline__ int swzB(int px) {
  return (((px & 7) ^ ((px >> 3) & 7)) << 4);
}

__global__ __launch_bounds__(512, 4) void fused_k(
    const float* __restrict__ x, const __bf16* __restrict__ Wf,
    const __bf16* __restrict__ W2f,
    const float* __restrict__ b_lr, const float* __restrict__ b_du,
    float* __restrict__ out)
{
  __shared__ __align__(16) char smem[49152 + 16384];
  char* Tlds = smem;                 // 64 px * 768 B (384 k bf16), swizzled
  char* buf0 = smem + 49152;         // 64 px * 128 B
  char* buf1 = smem + 49152 + 8192;

  const int tid  = threadIdx.x;
  const int lane = tid & 63;
  const int wv   = tid >> 6;          // 0..7
  const int l15  = lane & 15, lg = lane >> 4;

  const int p0      = blockIdx.x * 64;
  const int img     = p0 >> 12;
  const int pixbase = p0 & 4095;
  const float* xb   = x + (size_t)img * (512 * 4096) + pixbase;
  const char* Wfb   = (const char*)Wf;
  const char* W2b   = (const char*)W2f;

  // staging: all 512 threads; 4 px x 2 k each (two f32x4 loads, 4x u32 writes)
  const int sp4 = (tid & 15) * 4;     // pixel quad
  const int skp = (tid >> 4) * 2;     // k pair, 0..62

  auto issueS = [&](int kt, f32x4* ldv) {
    ldv[0] = *(const f32x4*)(xb + (size_t)(kt * 64 + skp) * 4096 + sp4);
    ldv[1] = *(const f32x4*)(xb + (size_t)(kt * 64 + skp + 1) * 4096 + sp4);
  };
  auto writeS = [&](const f32x4* ldv, char* bw) {
    #pragma unroll
    for (int pi = 0; pi < 4; ++pi) {
      int px = sp4 + pi;
      union { __bf16 b[2]; unsigned int u; } wd;
      wd.b[0] = (__bf16)ldv[0][pi];
      wd.b[1] = (__bf16)ldv[1][pi];
      *(unsigned int*)(bw + px * 128 + ((skp * 2) ^ swzB(px))) = wd.u;
    }
  };

  // ---------------- phase 1: T = f(Wbig @ x_tile) ----------------
  f32x4 acc1[3][4] = {};

  auto compute1 = [&](int kt, const char* bbuf) {
    bf16x8 af[2][3];
    #pragma unroll
    for (int ks = 0; ks < 2; ++ks)
      #pragma unroll
      for (int i = 0; i < 3; ++i)
        af[ks][i] = *(const bf16x8*)(Wfb +
            (((kt * 2 + ks) * 24 + wv * 3 + i) << 10) + lane * 16);
    #pragma unroll
    for (int ks = 0; ks < 2; ++ks) {
      bf16x8 bfr[4];
      #pragma unroll
      for (int j = 0; j < 4; ++j) {
        int rb = j * 16 + l15;
        bfr[j] = *(const bf16x8*)(bbuf + rb * 128 +
                                  ((ks * 64 + lg * 16) ^ swzB(rb)));
      }
      #pragma unroll
      for (int i = 0; i < 3; ++i)
        #pragma unroll
        for (int j = 0; j < 4; ++j)
          acc1[i][j] = __builtin_amdgcn_mfma_f32_16x16x32_bf16(
              af[ks][i], bfr[j], acc1[i][j], 0, 0, 0);
    }
  };

  f32x4 ldA[2], ldB[2];
  issueS(0, ldA);                 // kt 0 -> ldA
  issueS(1, ldB);                 // kt 1 -> ldB
  writeS(ldA, buf0);              // compiler: vmcnt(2) (kt-1 loads in flight)
  BAR();

  #pragma unroll 1
  for (int kt2 = 0; kt2 < 8; kt2 += 2) {
    // even kt = kt2 : compute buf0
    if (kt2 < 6) issueS(kt2 + 2, ldA);
    compute1(kt2, buf0);
    writeS(ldB, buf1);            // kt2+1 data; kt2+2 loads stay in flight
    BAR();
    // odd kt = kt2+1 : compute buf1
    if (kt2 < 5) issueS(kt2 + 3, ldB);
    compute1(kt2 + 1, buf1);
    if (kt2 < 6) { writeS(ldA, buf0); BAR(); }
  }

  // epilogue 1: bias+relu rows>=128, write T' to Tlds [px][384] bf16
  #pragma unroll
  for (int i = 0; i < 3; ++i) {
    int m0 = wv * 48 + i * 16 + lg * 4;
    bool rl = (m0 >= 128);
    const float* bp = (m0 >= 256) ? (b_du + (m0 - 256)) : (b_lr + (m0 - 128));
    float b0 = 0.f, b1 = 0.f, b2 = 0.f, b3 = 0.f;
    if (rl) { b0 = bp[0]; b1 = bp[1]; b2 = bp[2]; b3 = bp[3]; }
    #pragma unroll
    for (int j = 0; j < 4; ++j) {
      int p = j * 16 + l15;
      union { __bf16 b[4]; u32x2 u; } wd;
      float v0 = acc1[i][j][0], v1 = acc1[i][j][1];
      float v2 = acc1[i][j][2], v3 = acc1[i][j][3];
      if (rl) {
        v0 = fmaxf(v0 + b0, 0.f); v1 = fmaxf(v1 + b1, 0.f);
        v2 = fmaxf(v2 + b2, 0.f); v3 = fmaxf(v3 + b3, 0.f);
      }
      wd.b[0] = (__bf16)v0; wd.b[1] = (__bf16)v1;
      wd.b[2] = (__bf16)v2; wd.b[3] = (__bf16)v3;
      *(u32x2*)(Tlds + p * 768 + ((m0 * 2) ^ ((p & 7) << 4))) = wd.u;
    }
  }
  BAR();

  // ---------------- phase 2: out = W2 @ T (barrier-free K loop) -------------
  f32x4 acc2[4][4] = {};
  bf16x8 afA[4], afB[4];
  #pragma unroll
  for (int i = 0; i < 4; ++i)
    afA[i] = *(const bf16x8*)(W2b + ((0 * 32 + wv * 4 + i) << 10) + lane * 16);

  #pragma unroll 1
  for (int g2 = 0; g2 < 6; ++g2) {
    int gA = 2 * g2, gB = 2 * g2 + 1;
    #pragma unroll
    for (int i = 0; i < 4; ++i)
      afB[i] = *(const bf16x8*)(W2b + ((gB * 32 + wv * 4 + i) << 10) + lane * 16);
    {
      bf16x8 bfr[4];
      #pragma unroll
      for (int j = 0; j < 4; ++j) {
        int rb = j * 16 + l15;
        bfr[j] = *(const bf16x8*)(Tlds + rb * 768 +
                                  ((gA * 64 + lg * 16) ^ ((rb & 7) << 4)));
      }
      #pragma unroll
      for (int i = 0; i < 4; ++i)
        #pragma unroll
        for (int j = 0; j < 4; ++j)
          acc2[i][j] = __builtin_amdgcn_mfma_f32_16x16x32_bf16(
              afA[i], bfr[j], acc2[i][j], 0, 0, 0);
    }
    if (g2 < 5) {
      #pragma unroll
      for (int i = 0; i < 4; ++i)
        afA[i] = *(const bf16x8*)(W2b + (((gA + 2) * 32 + wv * 4 + i) << 10) + lane * 16);
    }
    {
      bf16x8 bfr[4];
      #pragma unroll
      for (int j = 0; j < 4; ++j) {
        int rb = j * 16 + l15;
        bfr[j] = *(const bf16x8*)(Tlds + rb * 768 +
                                  ((gB * 64 + lg * 16) ^ ((rb & 7) << 4)));
      }
      #pragma unroll
      for (int i = 0; i < 4; ++i)
        #pragma unroll
        for (int j = 0; j < 4; ++j)
          acc2[i][j] = __builtin_amdgcn_mfma_f32_16x16x32_bf16(
              afB[i], bfr[j], acc2[i][j], 0, 0, 0);
    }
  }

  // epilogue 2: pixel-shuffle scatter. row r = beta*256 + irow*2 + gamma.
  #pragma unroll
  for (int i = 0; i < 4; ++i) {
    int r = (wv * 4 + i) * 16 + lg * 4;   // even
    int beta = r >> 8;
    int irow = (r >> 1) & 127;
    #pragma unroll
    for (int j = 0; j < 4; ++j) {
      int pp = pixbase + j * 16 + l15;
      int h = pp >> 6, w = pp & 63;
      size_t o0 = ((((size_t)img * 128 + irow) * 128) + (2 * h + beta)) * 128
                  + 2 * w;
      f32x2 lo; lo.x = acc2[i][j][0]; lo.y = acc2[i][j][1];
      f32x2 hi; hi.x = acc2[i][j][2]; hi.y = acc2[i][j][3];
      *(f32x2*)(out + o0)         = lo;   // channel irow
      *(f32x2*)(out + o0 + 16384) = hi;   // channel irow+1
    }
  }
}

// ---------------- launcher ---------------------------------------------------

extern "C" void kernel_launch(void* const* d_in, const int* in_sizes, int n_in,
                              void* d_out, int out_size, void* d_ws, size_t ws_size,
                              hipStream_t stream) {
  const float* x     = (const float*)d_in[0];
  const float* w_du  = (const float*)d_in[1];
  const float* b_du  = (const float*)d_in[2];
  const float* w_lr  = (const float*)d_in[3];
  const float* b_lr  = (const float*)d_in[4];
  const float* w_1x1 = (const float*)d_in[5];
  const float* w_ch  = (const float*)d_in[6];
  const float* w_w   = (const float*)d_in[7];
  const float* w_H   = (const float*)d_in[8];
  float* out = (float*)d_out;

  char* ws = (char*)d_ws;
  __bf16* Wf  = (__bf16*)(ws + 0);        // 16*24*1024 = 393216
  __bf16* W2f = (__bf16*)(ws + 393216);   // 12*32*1024 = 393216
  if (ws_size < (size_t)786432) return;

  prep_k <<<1024, 256, 0, stream>>>(w_ch, w_1x1, w_lr, w_du, w_H, w_w, Wf, W2f);
  fused_k<<<512, 512, 0, stream>>>(x, Wf, W2f, b_lr, b_du, out);
}

// Round 5
// 48.259 us; speedup vs baseline: 2.2139x; 1.0765x over previous
//
#include <hip/hip_runtime.h>
#include <hip/hip_bf16.h>
#include <stdint.h>
#include <stddef.h>

// ---------------------------------------------------------------------------
// SSRupsampling3 == two small GEMMs:
//   T  = f(Wbig[384x512] @ x)     (relu+bias rows 128..383)
//   out= W2[512x384] @ T          (+ pixel-shuffle scatter)
// R5: R4's raw-barrier pipeline with register pressure cut below the spill
// line: 1-deep x prefetch (8 VGPRs), per-ks A fragments (12 VGPRs), phase 2
// reverted to R3's proven form. s_setprio around MFMA clusters (T5).
// ---------------------------------------------------------------------------

typedef __attribute__((ext_vector_type(8))) __bf16 bf16x8;
typedef __attribute__((ext_vector_type(4))) float  f32x4;
typedef __attribute__((ext_vector_type(2))) float  f32x2;
typedef __attribute__((ext_vector_type(4))) unsigned int u32x4;
typedef __attribute__((ext_vector_type(2))) unsigned int u32x2;

// LDS-only cross-wave dataflow -> lgkmcnt(0)+s_barrier suffices; keeps
// global prefetch loads in flight across the barrier (T3/T4).
#define BAR() asm volatile("s_waitcnt lgkmcnt(0)\n\ts_barrier" ::: "memory")

// A-fragment layout for mfma_f32_16x16x32_bf16 (verified R1-R4):
//   lane l holds A[row = mfrag*16 + (l&15)][k = gks*32 + (l>>4)*8 + j]
// Stored as frag[(gks*NMF + mfrag)*512 + lane*8 + j] (bf16).

// ---------------- prep kernel (unchanged from R4, ~5 us) --------------------

__global__ __launch_bounds__(256) void prep_k(
    const float* __restrict__ w_ch, const float* __restrict__ w_1x1,
    const float* __restrict__ w_lr, const float* __restrict__ w_du,
    const float* __restrict__ w_H,  const float* __restrict__ w_w,
    __bf16* __restrict__ Wf, __bf16* __restrict__ W2f)
{
  __shared__ float wh[2][128];
  __shared__ float Mrow[2][128];
  int bid = blockIdx.x;
  if (bid < 768) {
    int gid = bid * 256 + threadIdx.x;       // 196608 = 384*512
    int r = gid >> 9, c = gid & 511;
    float v;
    if (r < 128) {                            // w_ch[:, :128] @ w_1x1
      const float* a_ = w_ch + r * 384;
      const float* b_ = w_1x1 + c;
      float s0 = 0.f, s1 = 0.f, s2 = 0.f, s3 = 0.f;
      #pragma unroll
      for (int j = 0; j < 128; j += 4) {
        s0 += a_[j + 0] * b_[(size_t)(j + 0) * 512];
        s1 += a_[j + 1] * b_[(size_t)(j + 1) * 512];
        s2 += a_[j + 2] * b_[(size_t)(j + 2) * 512];
        s3 += a_[j + 3] * b_[(size_t)(j + 3) * 512];
      }
      v = (s0 + s1) + (s2 + s3);
    } else if (r < 256) {
      v = w_lr[(r - 128) * 1536 + c * 3 + 1]; // center tap (1,3)
    } else {
      v = w_du[(r - 256) * 1536 + c * 3 + 1]; // center tap (3,1)
    }
    int gks = c >> 5, lsub = (c >> 3) & 3, jj = c & 7;
    int mfrag = r >> 4, lrow = r & 15;
    Wf[((gks * 24 + mfrag) << 9) + ((lrow + 16 * lsub) << 3) + jj] = (__bf16)v;
  } else {
    int t = threadIdx.x & 127, half = threadIdx.x >> 7;
    int r = (bid - 768) * 2 + half;           // W2 row, 0..511
    int beta = r >> 8, gam = r & 1, irow = (r >> 1) & 127;
    wh[half][t] = w_H[(gam * 128 + irow) * 128 + t];
    __syncthreads();
    {
      const float* ww = w_w + beta * 16384 + t;
      float s0 = 0.f, s1 = 0.f, s2 = 0.f, s3 = 0.f;
      #pragma unroll
      for (int s = 0; s < 128; s += 4) {
        s0 += wh[half][s + 0] * ww[(s + 0) * 128];
        s1 += wh[half][s + 1] * ww[(s + 1) * 128];
        s2 += wh[half][s + 2] * ww[(s + 2) * 128];
        s3 += wh[half][s + 3] * ww[(s + 3) * 128];
      }
      Mrow[half][t] = (s0 + s1) + (s2 + s3);
    }
    __syncthreads();
    int mfrag = r >> 4, lrow = r & 15;
    #pragma unroll
    for (int c0 = 0; c0 < 384; c0 += 128) {
      int col = c0 + t;
      float v;
      if (c0 == 0) {
        v = Mrow[half][t];
      } else {
        const float* wc = w_ch + col;
        float s0 = 0.f, s1 = 0.f, s2 = 0.f, s3 = 0.f;
        #pragma unroll
        for (int k = 0; k < 128; k += 4) {
          s0 += Mrow[half][k + 0] * wc[(k + 0) * 384];
          s1 += Mrow[half][k + 1] * wc[(k + 1) * 384];
          s2 += Mrow[half][k + 2] * wc[(k + 2) * 384];
          s3 += Mrow[half][k + 3] * wc[(k + 3) * 384];
        }
        v = (s0 + s1) + (s2 + s3);
      }
      int gks = col >> 5, lsub = (col >> 3) & 3, jj = col & 7;
      W2f[((gks * 32 + mfrag) << 9) + ((lrow + 16 * lsub) << 3) + jj] = (__bf16)v;
    }
  }
}

// ---------------- fused kernel ----------------------------------------------

__device__ __forceinline__ int swzB(int px) {
  return (((px & 7) ^ ((px >> 3) & 7)) << 4);
}

__global__ __launch_bounds__(512, 4) void fused_k(
    const float* __restrict__ x, const __bf16* __restrict__ Wf,
    const __bf16* __restrict__ W2f,
    const float* __restrict__ b_lr, const float* __restrict__ b_du,
    float* __restrict__ out)
{
  __shared__ __align__(16) char smem[49152 + 16384];
  char* Tlds = smem;                 // 64 px * 768 B (384 k bf16), swizzled
  char* buf0 = smem + 49152;         // 64 px * 128 B
  char* buf1 = smem + 49152 + 8192;

  const int tid  = threadIdx.x;
  const int lane = tid & 63;
  const int wv   = tid >> 6;          // 0..7
  const int l15  = lane & 15, lg = lane >> 4;

  const int p0      = blockIdx.x * 64;
  const int img     = p0 >> 12;
  const int pixbase = p0 & 4095;
  const float* xb   = x + (size_t)img * (512 * 4096) + pixbase;
  const char* Wfb   = (const char*)Wf;
  const char* W2b   = (const char*)W2f;

  // staging: all 512 threads; 4 px x 2 k each (two f32x4 loads, 4x u32 writes)
  const int sp4 = (tid & 15) * 4;     // pixel quad
  const int skp = (tid >> 4) * 2;     // k pair, 0..62

  f32x4 ldv[2];
  auto issueS = [&](int kt) {
    ldv[0] = *(const f32x4*)(xb + (size_t)(kt * 64 + skp) * 4096 + sp4);
    ldv[1] = *(const f32x4*)(xb + (size_t)(kt * 64 + skp + 1) * 4096 + sp4);
  };
  auto writeS = [&](char* bw) {
    #pragma unroll
    for (int pi = 0; pi < 4; ++pi) {
      int px = sp4 + pi;
      union { __bf16 b[2]; unsigned int u; } wd;
      wd.b[0] = (__bf16)ldv[0][pi];
      wd.b[1] = (__bf16)ldv[1][pi];
      *(unsigned int*)(bw + px * 128 + ((skp * 2) ^ swzB(px))) = wd.u;
    }
  };

  // ---------------- phase 1: T = f(Wbig @ x_tile) ----------------
  f32x4 acc1[3][4] = {};

  auto compute1 = [&](int kt, const char* bbuf) {
    #pragma unroll
    for (int ks = 0; ks < 2; ++ks) {
      bf16x8 af[3];
      #pragma unroll
      for (int i = 0; i < 3; ++i)
        af[i] = *(const bf16x8*)(Wfb +
            (((kt * 2 + ks) * 24 + wv * 3 + i) << 10) + lane * 16);
      bf16x8 bfr[4];
      #pragma unroll
      for (int j = 0; j < 4; ++j) {
        int rb = j * 16 + l15;
        bfr[j] = *(const bf16x8*)(bbuf + rb * 128 +
                                  ((ks * 64 + lg * 16) ^ swzB(rb)));
      }
      __builtin_amdgcn_s_setprio(1);
      #pragma unroll
      for (int i = 0; i < 3; ++i)
        #pragma unroll
        for (int j = 0; j < 4; ++j)
          acc1[i][j] = __builtin_amdgcn_mfma_f32_16x16x32_bf16(
              af[i], bfr[j], acc1[i][j], 0, 0, 0);
      __builtin_amdgcn_s_setprio(0);
    }
  };

  issueS(0);
  writeS(buf0);          // vmcnt wait for ldv inside
  issueS(1);             // kt=1 loads fly across the barrier
  BAR();

  #pragma unroll 1
  for (int kt = 0; kt < 8; ++kt) {
    const char* bcur = (kt & 1) ? buf1 : buf0;
    char* bnext      = (kt & 1) ? buf0 : buf1;
    compute1(kt, bcur);
    if (kt < 7) {
      writeS(bnext);               // consumes ldv (kt+1 data)
      if (kt < 6) issueS(kt + 2);  // next loads in flight across BAR
      BAR();
    }
  }

  // epilogue 1: bias+relu rows>=128, write T' to Tlds [px][384] bf16
  #pragma unroll
  for (int i = 0; i < 3; ++i) {
    int m0 = wv * 48 + i * 16 + lg * 4;
    bool rl = (m0 >= 128);
    const float* bp = (m0 >= 256) ? (b_du + (m0 - 256)) : (b_lr + (m0 - 128));
    float b0 = 0.f, b1 = 0.f, b2 = 0.f, b3 = 0.f;
    if (rl) { b0 = bp[0]; b1 = bp[1]; b2 = bp[2]; b3 = bp[3]; }
    #pragma unroll
    for (int j = 0; j < 4; ++j) {
      int p = j * 16 + l15;
      union { __bf16 b[4]; u32x2 u; } wd;
      float v0 = acc1[i][j][0], v1 = acc1[i][j][1];
      float v2 = acc1[i][j][2], v3 = acc1[i][j][3];
      if (rl) {
        v0 = fmaxf(v0 + b0, 0.f); v1 = fmaxf(v1 + b1, 0.f);
        v2 = fmaxf(v2 + b2, 0.f); v3 = fmaxf(v3 + b3, 0.f);
      }
      wd.b[0] = (__bf16)v0; wd.b[1] = (__bf16)v1;
      wd.b[2] = (__bf16)v2; wd.b[3] = (__bf16)v3;
      *(u32x2*)(Tlds + p * 768 + ((m0 * 2) ^ ((p & 7) << 4))) = wd.u;
    }
  }
  BAR();

  // ---------------- phase 2: out = W2 @ T (barrier-free K loop) -------------
  f32x4 acc2[4][4] = {};
  bf16x8 afA[4], afB[4];
  #pragma unroll
  for (int i = 0; i < 4; ++i)
    afA[i] = *(const bf16x8*)(W2b + ((0 * 32 + wv * 4 + i) << 10) + lane * 16);

  #pragma unroll 1
  for (int g2 = 0; g2 < 6; ++g2) {
    int gA = 2 * g2, gB = 2 * g2 + 1;
    #pragma unroll
    for (int i = 0; i < 4; ++i)
      afB[i] = *(const bf16x8*)(W2b + ((gB * 32 + wv * 4 + i) << 10) + lane * 16);
    {
      bf16x8 bfr[4];
      #pragma unroll
      for (int j = 0; j < 4; ++j) {
        int rb = j * 16 + l15;
        bfr[j] = *(const bf16x8*)(Tlds + rb * 768 +
                                  ((gA * 64 + lg * 16) ^ ((rb & 7) << 4)));
      }
      __builtin_amdgcn_s_setprio(1);
      #pragma unroll
      for (int i = 0; i < 4; ++i)
        #pragma unroll
        for (int j = 0; j < 4; ++j)
          acc2[i][j] = __builtin_amdgcn_mfma_f32_16x16x32_bf16(
              afA[i], bfr[j], acc2[i][j], 0, 0, 0);
      __builtin_amdgcn_s_setprio(0);
    }
    if (g2 < 5) {
      #pragma unroll
      for (int i = 0; i < 4; ++i)
        afA[i] = *(const bf16x8*)(W2b + (((gA + 2) * 32 + wv * 4 + i) << 10) + lane * 16);
    }
    {
      bf16x8 bfr[4];
      #pragma unroll
      for (int j = 0; j < 4; ++j) {
        int rb = j * 16 + l15;
        bfr[j] = *(const bf16x8*)(Tlds + rb * 768 +
                                  ((gB * 64 + lg * 16) ^ ((rb & 7) << 4)));
      }
      __builtin_amdgcn_s_setprio(1);
      #pragma unroll
      for (int i = 0; i < 4; ++i)
        #pragma unroll
        for (int j = 0; j < 4; ++j)
          acc2[i][j] = __builtin_amdgcn_mfma_f32_16x16x32_bf16(
              afB[i], bfr[j], acc2[i][j], 0, 0, 0);
      __builtin_amdgcn_s_setprio(0);
    }
  }

  // epilogue 2: pixel-shuffle scatter. row r = beta*256 + irow*2 + gamma.
  #pragma unroll
  for (int i = 0; i < 4; ++i) {
    int r = (wv * 4 + i) * 16 + lg * 4;   // even
    int beta = r >> 8;
    int irow = (r >> 1) & 127;
    #pragma unroll
    for (int j = 0; j < 4; ++j) {
      int pp = pixbase + j * 16 + l15;
      int h = pp >> 6, w = pp & 63;
      size_t o0 = ((((size_t)img * 128 + irow) * 128) + (2 * h + beta)) * 128
                  + 2 * w;
      f32x2 lo; lo.x = acc2[i][j][0]; lo.y = acc2[i][j][1];
      f32x2 hi; hi.x = acc2[i][j][2]; hi.y = acc2[i][j][3];
      *(f32x2*)(out + o0)         = lo;   // channel irow
      *(f32x2*)(out + o0 + 16384) = hi;   // channel irow+1
    }
  }
}

// ---------------- launcher ---------------------------------------------------

extern "C" void kernel_launch(void* const* d_in, const int* in_sizes, int n_in,
                              void* d_out, int out_size, void* d_ws, size_t ws_size,
                              hipStream_t stream) {
  const float* x     = (const float*)d_in[0];
  const float* w_du  = (const float*)d_in[1];
  const float* b_du  = (const float*)d_in[2];
  const float* w_lr  = (const float*)d_in[3];
  const float* b_lr  = (const float*)d_in[4];
  const float* w_1x1 = (const float*)d_in[5];
  const float* w_ch  = (const float*)d_in[6];
  const float* w_w   = (const float*)d_in[7];
  const float* w_H   = (const float*)d_in[8];
  float* out = (float*)d_out;

  char* ws = (char*)d_ws;
  __bf16* Wf  = (__bf16*)(ws + 0);        // 16*24*1024 = 393216
  __bf16* W2f = (__bf16*)(ws + 393216);   // 12*32*1024 = 393216
  if (ws_size < (size_t)786432) return;

  prep_k <<<1024, 256, 0, stream>>>(w_ch, w_1x1, w_lr, w_du, w_H, w_w, Wf, W2f);
  fused_k<<<512, 512, 0, stream>>>(x, Wf, W2f, b_lr, b_du, out);
}

// Round 6
// 47.825 us; speedup vs baseline: 2.2340x; 1.0091x over previous
//
#include <hip/hip_runtime.h>
#include <hip/hip_bf16.h>
#include <stdint.h>
#include <stddef.h>

// ---------------------------------------------------------------------------
// SSRupsampling3 == two small GEMMs:
//   T  = f(Wbig[384x512] @ x)     (relu+bias rows 128..383)
//   out= W2[512x384] @ T          (+ pixel-shuffle scatter)
// R6: 128 px/block (256 blocks, 1 block/CU) halves per-CU weight L2 traffic.
// BK=32 staging (1 ds_write_b128/thread, XOR slot swizzle), 2-deep x
// prefetch, 1-ahead weight-frag prefetch both phases, raw lgkm barriers.
// ---------------------------------------------------------------------------

typedef __attribute__((ext_vector_type(8))) __bf16 bf16x8;
typedef __attribute__((ext_vector_type(4))) float  f32x4;
typedef __attribute__((ext_vector_type(2))) float  f32x2;
typedef __attribute__((ext_vector_type(4))) unsigned int u32x4;
typedef __attribute__((ext_vector_type(2))) unsigned int u32x2;

#define BAR() asm volatile("s_waitcnt lgkmcnt(0)\n\ts_barrier" ::: "memory")

// A-fragment layout for mfma_f32_16x16x32_bf16 (verified R1-R5):
//   lane l holds A[row = mfrag*16 + (l&15)][k = gks*32 + (l>>4)*8 + j]
// Stored as frag[(gks*NMF + mfrag)*512 + lane*8 + j] (bf16).

// ---------------- prep kernel (unchanged from R4/R5, ~5 us) -----------------

__global__ __launch_bounds__(256) void prep_k(
    const float* __restrict__ w_ch, const float* __restrict__ w_1x1,
    const float* __restrict__ w_lr, const float* __restrict__ w_du,
    const float* __restrict__ w_H,  const float* __restrict__ w_w,
    __bf16* __restrict__ Wf, __bf16* __restrict__ W2f)
{
  __shared__ float wh[2][128];
  __shared__ float Mrow[2][128];
  int bid = blockIdx.x;
  if (bid < 768) {
    int gid = bid * 256 + threadIdx.x;       // 196608 = 384*512
    int r = gid >> 9, c = gid & 511;
    float v;
    if (r < 128) {                            // w_ch[:, :128] @ w_1x1
      const float* a_ = w_ch + r * 384;
      const float* b_ = w_1x1 + c;
      float s0 = 0.f, s1 = 0.f, s2 = 0.f, s3 = 0.f;
      #pragma unroll
      for (int j = 0; j < 128; j += 4) {
        s0 += a_[j + 0] * b_[(size_t)(j + 0) * 512];
        s1 += a_[j + 1] * b_[(size_t)(j + 1) * 512];
        s2 += a_[j + 2] * b_[(size_t)(j + 2) * 512];
        s3 += a_[j + 3] * b_[(size_t)(j + 3) * 512];
      }
      v = (s0 + s1) + (s2 + s3);
    } else if (r < 256) {
      v = w_lr[(r - 128) * 1536 + c * 3 + 1]; // center tap (1,3)
    } else {
      v = w_du[(r - 256) * 1536 + c * 3 + 1]; // center tap (3,1)
    }
    int gks = c >> 5, lsub = (c >> 3) & 3, jj = c & 7;
    int mfrag = r >> 4, lrow = r & 15;
    Wf[((gks * 24 + mfrag) << 9) + ((lrow + 16 * lsub) << 3) + jj] = (__bf16)v;
  } else {
    int t = threadIdx.x & 127, half = threadIdx.x >> 7;
    int r = (bid - 768) * 2 + half;           // W2 row, 0..511
    int beta = r >> 8, gam = r & 1, irow = (r >> 1) & 127;
    wh[half][t] = w_H[(gam * 128 + irow) * 128 + t];
    __syncthreads();
    {
      const float* ww = w_w + beta * 16384 + t;
      float s0 = 0.f, s1 = 0.f, s2 = 0.f, s3 = 0.f;
      #pragma unroll
      for (int s = 0; s < 128; s += 4) {
        s0 += wh[half][s + 0] * ww[(s + 0) * 128];
        s1 += wh[half][s + 1] * ww[(s + 1) * 128];
        s2 += wh[half][s + 2] * ww[(s + 2) * 128];
        s3 += wh[half][s + 3] * ww[(s + 3) * 128];
      }
      Mrow[half][t] = (s0 + s1) + (s2 + s3);
    }
    __syncthreads();
    int mfrag = r >> 4, lrow = r & 15;
    #pragma unroll
    for (int c0 = 0; c0 < 384; c0 += 128) {
      int col = c0 + t;
      float v;
      if (c0 == 0) {
        v = Mrow[half][t];
      } else {
        const float* wc = w_ch + col;
        float s0 = 0.f, s1 = 0.f, s2 = 0.f, s3 = 0.f;
        #pragma unroll
        for (int k = 0; k < 128; k += 4) {
          s0 += Mrow[half][k + 0] * wc[(k + 0) * 384];
          s1 += Mrow[half][k + 1] * wc[(k + 1) * 384];
          s2 += Mrow[half][k + 2] * wc[(k + 2) * 384];
          s3 += Mrow[half][k + 3] * wc[(k + 3) * 384];
        }
        v = (s0 + s1) + (s2 + s3);
      }
      int gks = col >> 5, lsub = (col >> 3) & 3, jj = col & 7;
      W2f[((gks * 32 + mfrag) << 9) + ((lrow + 16 * lsub) << 3) + jj] = (__bf16)v;
    }
  }
}

// ---------------- fused kernel ----------------------------------------------

// staging-buffer slot swizzle: rows of 64 B (32 k bf16), 4 slots of 16 B.
// slot(px) must differ for px, px+16, px+32, px+48 (read aliasing) and for
// the 4-px strides of the write pattern -> fold bits 0-1, 2-3, 4-5.
__device__ __forceinline__ int slotS(int px) {
  return ((px & 3) ^ ((px >> 2) & 3) ^ ((px >> 4) & 3)) << 4;
}

__global__ __launch_bounds__(512, 2) void fused_k(
    const float* __restrict__ x, const __bf16* __restrict__ Wf,
    const __bf16* __restrict__ W2f,
    const float* __restrict__ b_lr, const float* __restrict__ b_du,
    float* __restrict__ out)
{
  __shared__ __align__(16) char smem[98304 + 16384];
  char* Tlds = smem;                 // 128 px * 768 B (384 k bf16), swizzled
  char* buf0 = smem + 98304;         // 128 px * 64 B (32 k bf16)
  char* buf1 = smem + 98304 + 8192;

  const int tid  = threadIdx.x;
  const int lane = tid & 63;
  const int wv   = tid >> 6;          // 0..7
  const int l15  = lane & 15, lg = lane >> 4;

  const int p0      = blockIdx.x * 128;
  const int img     = p0 >> 12;
  const int pixbase = p0 & 4095;
  const float* xb   = x + (size_t)img * (512 * 4096) + pixbase;
  const char* Wfb   = (const char*)Wf;
  const char* W2b   = (const char*)W2f;

  // staging: 512 threads; thread = (px, k-octet). 8 coalesced dword loads,
  // one ds_write_b128 of 8 bf16.
  const int s_px = tid & 127;
  const int s_k8 = (tid >> 7) * 8;     // 0,8,16,24

  float ldA[8], ldB[8];
  auto issueS = [&](int kt, float* ldv) {
    #pragma unroll
    for (int j = 0; j < 8; ++j)
      ldv[j] = xb[(size_t)(kt * 32 + s_k8 + j) * 4096 + s_px];
  };
  auto writeS = [&](const float* ldv, char* bw) {
    union { __bf16 b[8]; u32x4 u; } wd;
    #pragma unroll
    for (int j = 0; j < 8; ++j) wd.b[j] = (__bf16)ldv[j];
    *(u32x4*)(bw + s_px * 64 + ((s_k8 * 2) ^ slotS(s_px))) = wd.u;
  };

  // ---------------- phase 1: T = f(Wbig @ x_tile) ----------------
  f32x4 acc1[3][8] = {};
  bf16x8 afA[3], afB[3];

  auto loadAf1 = [&](int kt, bf16x8* af) {
    #pragma unroll
    for (int i = 0; i < 3; ++i)
      af[i] = *(const bf16x8*)(Wfb + ((kt * 24 + wv * 3 + i) << 10) + lane * 16);
  };
  auto compute1 = [&](const bf16x8* af, const char* bbuf) {
    bf16x8 bfr[8];
    #pragma unroll
    for (int j = 0; j < 8; ++j) {
      int rb = j * 16 + l15;
      bfr[j] = *(const bf16x8*)(bbuf + rb * 64 + ((lg * 16) ^ slotS(rb)));
    }
    __builtin_amdgcn_s_setprio(1);
    #pragma unroll
    for (int i = 0; i < 3; ++i)
      #pragma unroll
      for (int j = 0; j < 8; ++j)
        acc1[i][j] = __builtin_amdgcn_mfma_f32_16x16x32_bf16(
            af[i], bfr[j], acc1[i][j], 0, 0, 0);
    __builtin_amdgcn_s_setprio(0);
  };

  issueS(0, ldA);
  issueS(1, ldB);
  writeS(ldA, buf0);          // waits vmcnt for ldA internally
  issueS(2, ldA);             // kt=2 loads fly across the barrier
  loadAf1(0, afA);
  loadAf1(1, afB);
  BAR();

  #pragma unroll 1
  for (int kt2 = 0; kt2 < 16; kt2 += 2) {
    // even step kt2: data in buf0, weights in afA
    compute1(afA, buf0);
    if (kt2 < 14) loadAf1(kt2 + 2, afA);
    writeS(ldB, buf1);                    // kt2+1 -> buf1
    if (kt2 < 14) issueS(kt2 + 3, ldB);
    BAR();
    // odd step kt2+1: data in buf1, weights in afB
    compute1(afB, buf1);
    if (kt2 < 14) {
      loadAf1(kt2 + 3, afB);
      writeS(ldA, buf0);                  // kt2+2 -> buf0
      if (kt2 < 12) issueS(kt2 + 4, ldA);
      BAR();
    }
  }

  // epilogue 1: bias+relu rows>=128, write T' to Tlds [px][384] bf16
  #pragma unroll
  for (int i = 0; i < 3; ++i) {
    int m0 = wv * 48 + i * 16 + lg * 4;
    bool rl = (m0 >= 128);
    const float* bp = (m0 >= 256) ? (b_du + (m0 - 256)) : (b_lr + (m0 - 128));
    float b0 = 0.f, b1 = 0.f, b2 = 0.f, b3 = 0.f;
    if (rl) { b0 = bp[0]; b1 = bp[1]; b2 = bp[2]; b3 = bp[3]; }
    #pragma unroll
    for (int j = 0; j < 8; ++j) {
      int p = j * 16 + l15;
      union { __bf16 b[4]; u32x2 u; } wd;
      float v0 = acc1[i][j][0], v1 = acc1[i][j][1];
      float v2 = acc1[i][j][2], v3 = acc1[i][j][3];
      if (rl) {
        v0 = fmaxf(v0 + b0, 0.f); v1 = fmaxf(v1 + b1, 0.f);
        v2 = fmaxf(v2 + b2, 0.f); v3 = fmaxf(v3 + b3, 0.f);
      }
      wd.b[0] = (__bf16)v0; wd.b[1] = (__bf16)v1;
      wd.b[2] = (__bf16)v2; wd.b[3] = (__bf16)v3;
      *(u32x2*)(Tlds + p * 768 + ((m0 * 2) ^ ((p & 7) << 4))) = wd.u;
    }
  }
  // first phase-2 weight fragments: issue before the barrier (independent)
  f32x4 acc2[4][8] = {};
  bf16x8 af2A[4], af2B[4];
  #pragma unroll
  for (int i = 0; i < 4; ++i)
    af2A[i] = *(const bf16x8*)(W2b + ((0 * 32 + wv * 4 + i) << 10) + lane * 16);
  #pragma unroll
  for (int i = 0; i < 4; ++i)
    af2B[i] = *(const bf16x8*)(W2b + ((1 * 32 + wv * 4 + i) << 10) + lane * 16);
  BAR();

  // ---------------- phase 2: out = W2 @ T (barrier-free K loop) -------------
  #pragma unroll 1
  for (int g2 = 0; g2 < 6; ++g2) {
    int gA = 2 * g2, gB = 2 * g2 + 1;
    {
      bf16x8 bfr[8];
      #pragma unroll
      for (int j = 0; j < 8; ++j) {
        int rb = j * 16 + l15;
        bfr[j] = *(const bf16x8*)(Tlds + rb * 768 +
                                  ((gA * 64 + lg * 16) ^ ((rb & 7) << 4)));
      }
      __builtin_amdgcn_s_setprio(1);
      #pragma unroll
      for (int i = 0; i < 4; ++i)
        #pragma unroll
        for (int j = 0; j < 8; ++j)
          acc2[i][j] = __builtin_amdgcn_mfma_f32_16x16x32_bf16(
              af2A[i], bfr[j], acc2[i][j], 0, 0, 0);
      __builtin_amdgcn_s_setprio(0);
    }
    if (g2 < 5) {
      #pragma unroll
      for (int i = 0; i < 4; ++i)
        af2A[i] = *(const bf16x8*)(W2b + (((gA + 2) * 32 + wv * 4 + i) << 10) + lane * 16);
    }
    {
      bf16x8 bfr[8];
      #pragma unroll
      for (int j = 0; j < 8; ++j) {
        int rb = j * 16 + l15;
        bfr[j] = *(const bf16x8*)(Tlds + rb * 768 +
                                  ((gB * 64 + lg * 16) ^ ((rb & 7) << 4)));
      }
      __builtin_amdgcn_s_setprio(1);
      #pragma unroll
      for (int i = 0; i < 4; ++i)
        #pragma unroll
        for (int j = 0; j < 8; ++j)
          acc2[i][j] = __builtin_amdgcn_mfma_f32_16x16x32_bf16(
              af2B[i], bfr[j], acc2[i][j], 0, 0, 0);
      __builtin_amdgcn_s_setprio(0);
    }
    if (g2 < 5) {
      #pragma unroll
      for (int i = 0; i < 4; ++i)
        af2B[i] = *(const bf16x8*)(W2b + (((gB + 2) * 32 + wv * 4 + i) << 10) + lane * 16);
    }
  }

  // epilogue 2: pixel-shuffle scatter. row r = beta*256 + irow*2 + gamma.
  #pragma unroll
  for (int i = 0; i < 4; ++i) {
    int r = wv * 64 + i * 16 + lg * 4;   // even
    int beta = r >> 8;
    int irow = (r >> 1) & 127;
    #pragma unroll
    for (int j = 0; j < 8; ++j) {
      int pp = pixbase + j * 16 + l15;
      int h = pp >> 6, w = pp & 63;
      size_t o0 = ((((size_t)img * 128 + irow) * 128) + (2 * h + beta)) * 128
                  + 2 * w;
      f32x2 lo; lo.x = acc2[i][j][0]; lo.y = acc2[i][j][1];
      f32x2 hi; hi.x = acc2[i][j][2]; hi.y = acc2[i][j][3];
      *(f32x2*)(out + o0)         = lo;   // channel irow
      *(f32x2*)(out + o0 + 16384) = hi;   // channel irow+1
    }
  }
}

// ---------------- launcher ---------------------------------------------------

extern "C" void kernel_launch(void* const* d_in, const int* in_sizes, int n_in,
                              void* d_out, int out_size, void* d_ws, size_t ws_size,
                              hipStream_t stream) {
  const float* x     = (const float*)d_in[0];
  const float* w_du  = (const float*)d_in[1];
  const float* b_du  = (const float*)d_in[2];
  const float* w_lr  = (const float*)d_in[3];
  const float* b_lr  = (const float*)d_in[4];
  const float* w_1x1 = (const float*)d_in[5];
  const float* w_ch  = (const float*)d_in[6];
  const float* w_w   = (const float*)d_in[7];
  const float* w_H   = (const float*)d_in[8];
  float* out = (float*)d_out;

  char* ws = (char*)d_ws;
  __bf16* Wf  = (__bf16*)(ws + 0);        // 16*24*1024 = 393216
  __bf16* W2f = (__bf16*)(ws + 393216);   // 12*32*1024 = 393216
  if (ws_size < (size_t)786432) return;

  prep_k <<<1024, 256, 0, stream>>>(w_ch, w_1x1, w_lr, w_du, w_H, w_w, Wf, W2f);
  fused_k<<<256, 512, 0, stream>>>(x, Wf, W2f, b_lr, b_du, out);
}